// Round 14
// baseline (4931.401 us; speedup 1.0000x reference)
//
#include <hip/hip_runtime.h>
#include <cstdint>
#include <cstddef>

#define B_      16
#define N_      2048
#define NOTE_   512
#define BEAT_H_ 128
#define MEAS_H_ 64
#define NBEATS_ 256
#define NMEAS_  64
#define OUT_    11
#define D_      10
#define TSTRIDE 136   // fp16 Whh_t LDS row stride (halfs); bank-spread, 16B-aligned rows
// fin = 715 (512 note + 128 beat + 64 meas + 11 prev_out)

typedef float f32x4 __attribute__((ext_vector_type(4)));
typedef unsigned int u32x4 __attribute__((ext_vector_type(4)));
typedef _Float16 h2v __attribute__((ext_vector_type(2)));

__device__ __forceinline__ float fexp2_(float x) {
#if __has_builtin(__builtin_amdgcn_exp2f)
    return __builtin_amdgcn_exp2f(x);
#else
    return exp2f(x);
#endif
}
__device__ __forceinline__ float frcp_(float x) {
#if __has_builtin(__builtin_amdgcn_rcpf)
    return __builtin_amdgcn_rcpf(x);
#else
    return 1.0f / x;
#endif
}
__device__ __forceinline__ float sigm_(float x) {
    return frcp_(1.0f + fexp2_(-1.4426950408889634f * x));
}
__device__ __forceinline__ float tanh_(float x) {
    return 1.0f - 2.0f * frcp_(fexp2_(2.8853900817779268f * x) + 1.0f);
}

// LDS-only barrier (no vmcnt drain)
__device__ __forceinline__ void bar_lds_() {
    asm volatile("s_waitcnt lgkmcnt(0)\n\ts_barrier" ::: "memory");
}

__device__ __forceinline__ float dot2f_(unsigned wu, unsigned hu, float c) {
    union { unsigned u; h2v h; } a, bb;
    a.u = wu; bb.u = hu;
#if __has_builtin(__builtin_amdgcn_fdot2)
    return __builtin_amdgcn_fdot2(a.h, bb.h, c, false);
#else
    return c + (float)a.h[0] * (float)bb.h[0] + (float)a.h[1] * (float)bb.h[1];
#endif
}
// accumulate 4 dwords (8 fp16 pairs) of W·H into S
#define DQ(W, H, S)                                                           \
    do {                                                                      \
        S = dot2f_((W).x, (H).x, S); S = dot2f_((W).y, (H).y, S);             \
        S = dot2f_((W).z, (H).z, S); S = dot2f_((W).w, (H).w, S);             \
    } while (0)

// Folded recurrent weights (fp16): Whh_eff = Whh_f + Wih_f[:,705:715] @ W_fc
// bias_eff folded into finp rows i>0 ; wtail0 = Wih_f[:,704]
__device__ __align__(16) _Float16 g_whh_h16[512 * 128];
__device__ float g_bias_eff[512];
__device__ float g_wtail0[512];
__device__ __align__(16) _Float16 g_wht_h16[512 * TSTRIDE];

// ---------------------------------------------------------------------------
__global__ __launch_bounds__(256) void pad_k(const float* __restrict__ note,
                                             int* __restrict__ padf) {
    int wave = threadIdx.x >> 6, lane = threadIdx.x & 63;
    int r = blockIdx.x * 4 + wave;
    const float* row = note + ((size_t)r << 9);
    float s = 0.f;
#pragma unroll
    for (int u = 0; u < 8; ++u) s += row[lane + (u << 6)];
#pragma unroll
    for (int off = 32; off; off >>= 1) s += __shfl_xor(s, off, 64);
    if (lane == 0) padf[r] = (s == 0.0f) ? 1 : 0;
}

// ---------------------------------------------------------------------------
__global__ __launch_bounds__(128) void fold_whh(
    const float* __restrict__ Whh_f, const float* __restrict__ Wih_f,
    const float* __restrict__ W_fc, const float* __restrict__ b_fc) {
    int gr = blockIdx.x;   // 512
    int t = threadIdx.x;   // 128
    __shared__ float tail[OUT_];
    if (t < OUT_) tail[t] = Wih_f[(size_t)gr * 715 + 704 + t];
    __syncthreads();
    float m = Whh_f[(size_t)gr * 128 + t];
#pragma unroll
    for (int d = 0; d < D_; ++d) m += tail[1 + d] * W_fc[d * 128 + t];
    g_whh_h16[(size_t)gr * 128 + t] = (_Float16)m;
    if (t == 0) {
        float bb = 0.f;
#pragma unroll
        for (int d = 0; d < D_; ++d) bb += tail[1 + d] * b_fc[d];
        g_bias_eff[gr] = bb;
        g_wtail0[gr] = tail[0];
    }
}

// ---------------------------------------------------------------------------
__global__ __launch_bounds__(128) void fold_wht(const float* __restrict__ Whh_t) {
    int gr = blockIdx.x, t = threadIdx.x;
    g_wht_h16[(size_t)gr * TSTRIDE + t] = (_Float16)Whh_t[(size_t)gr * 128 + t];
    if (t < TSTRIDE - 128) g_wht_h16[(size_t)gr * TSTRIDE + 128 + t] = (_Float16)0.f;
}

// ---------------------------------------------------------------------------
__global__ __launch_bounds__(256) void tempo_pre_k(
    const float* __restrict__ beat, const float* __restrict__ meas,
    const int* __restrict__ bnum, const int* __restrict__ mnum,
    const float* __restrict__ Wih_t, const float* __restrict__ bih_t,
    const float* __restrict__ bhh_t, float* __restrict__ tpre) {
    __shared__ float sin_[16][192];
    int b = blockIdx.x, qt = blockIdx.y;
    int t = threadIdx.x;
    int bn0 = bnum[b << 11], mn0 = mnum[b << 11];
    for (int idx = t; idx < 16 * 192; idx += 256) {
        int qq = idx / 192, kk = idx - qq * 192;
        int q = qt * 16 + qq;
        float v;
        if (kk < 128) {
            v = beat[(size_t)(b * NBEATS_ + q) * 128 + kk];
        } else {
            int cm = ((q + bn0) >> 2) - mn0;
            if (cm > 63) cm = 63;
            if (cm < 0) cm = 0;
            v = meas[(size_t)(b * NMEAS_ + cm) * 64 + (kk - 128)];
        }
        sin_[qq][kk] = v;
    }
    __syncthreads();
    for (int half = 0; half < 2; ++half) {
        int j = t + half * 256;
        const float* wr = Wih_t + (size_t)j * 203;
        float bias = bih_t[j] + bhh_t[j];
        float acc[16] = {};
        for (int k = 0; k < 192; ++k) {
            float w = wr[k];
#pragma unroll
            for (int qq = 0; qq < 16; ++qq) acc[qq] += w * sin_[qq][k];
        }
        for (int qq = 0; qq < 16; ++qq)
            tpre[(size_t)(b * NBEATS_ + qt * 16 + qq) * 512 + j] = acc[qq] + bias;
    }
}

// ---------------------------------------------------------------------------
__global__ __launch_bounds__(256) void fin_pre_gemm(
    const float* __restrict__ note, const float* __restrict__ beat,
    const float* __restrict__ meas, const int* __restrict__ bnum,
    const int* __restrict__ mnum, const float* __restrict__ Wih_f,
    const float* __restrict__ bih_f, const float* __restrict__ bhh_f,
    float* __restrict__ finp) {
    __shared__ float As[16][64];
    __shared__ float Bs[16][64];
    int t = threadIdx.x;
    int r0 = blockIdx.x * 64;
    int j0 = blockIdx.y * 64;

    int am = t >> 2, alane = t & 3;
    int r = r0 + am;
    int b = r >> 11;
    int rb = b << 11;
    int cb = bnum[r] - bnum[rb];
    int cm = mnum[r] - mnum[rb];
    const float* arow_note = note + ((size_t)r << 9);
    const float* arow_beat = beat + ((size_t)(b * NBEATS_ + cb) << 7);
    const float* arow_meas = meas + ((size_t)(b * NMEAS_ + cm) << 6);

    int jj = t >> 2, blane = t & 3;
    const float* brow = Wih_f + (size_t)(j0 + jj) * 715;

    int tm0 = (t & 15) * 4, tn0 = (t >> 4) * 4;
    float acc[4][4] = {};

    for (int k0 = 0; k0 < 704; k0 += 16) {
        int ka = k0 + alane * 4;
        float4 av;
        if (ka < 512)      av = *(const float4*)(arow_note + ka);
        else if (ka < 640) av = *(const float4*)(arow_beat + (ka - 512));
        else               av = *(const float4*)(arow_meas + (ka - 640));
        int kb = k0 + blane * 4;
        float b0 = brow[kb], b1 = brow[kb + 1], b2 = brow[kb + 2], b3 = brow[kb + 3];
        __syncthreads();
        As[alane * 4 + 0][am] = av.x;
        As[alane * 4 + 1][am] = av.y;
        As[alane * 4 + 2][am] = av.z;
        As[alane * 4 + 3][am] = av.w;
        Bs[blane * 4 + 0][jj] = b0;
        Bs[blane * 4 + 1][jj] = b1;
        Bs[blane * 4 + 2][jj] = b2;
        Bs[blane * 4 + 3][jj] = b3;
        __syncthreads();
#pragma unroll
        for (int kk = 0; kk < 16; ++kk) {
            float4 a4 = *(const float4*)&As[kk][tm0];
            float4 b4 = *(const float4*)&Bs[kk][tn0];
            float aa[4] = {a4.x, a4.y, a4.z, a4.w};
            float bb[4] = {b4.x, b4.y, b4.z, b4.w};
#pragma unroll
            for (int mi = 0; mi < 4; ++mi)
#pragma unroll
                for (int ni = 0; ni < 4; ++ni) acc[mi][ni] += aa[mi] * bb[ni];
        }
    }
    float bias[4], beff[4];
#pragma unroll
    for (int ni = 0; ni < 4; ++ni) {
        int j = j0 + tn0 + ni;
        bias[ni] = bih_f[j] + bhh_f[j];
        beff[ni] = g_bias_eff[j];
    }
#pragma unroll
    for (int mi = 0; mi < 4; ++mi) {
        int rr = r0 + tm0 + mi;
        float eb = (rr & 2047) ? 1.0f : 0.0f;   // fold-bias only for i>0
        float4 o;
        o.x = acc[mi][0] + bias[0] + eb * beff[0];
        o.y = acc[mi][1] + bias[1] + eb * beff[1];
        o.z = acc[mi][2] + bias[2] + eb * beff[2];
        o.w = acc[mi][3] + bias[3] + eb * beff[3];
        *(float4*)(finp + ((size_t)rr << 9) + j0 + tn0) = o;
    }
}

// ---------------------------------------------------------------------------
// decoder: 384 threads = 4 gate waves + wave4 (output proj/stores) + wave5
// (attention). Gate wave w lane l: h-row = w*32+(l&31), K-half = l>>5.
// Each gate lane holds its 4 gate rows' K-half weights in 32 named u32x4
// (asm-touched). Gates/nonlin fully thread-local (c-state in regs); K-halves
// combined with in-wave shfl_xor(32). ONE LDS barrier per unchanged step.
// h/x ping-pong buffers avoid RW hazards across the single barrier.
// ---------------------------------------------------------------------------
__global__ __launch_bounds__(384)
__attribute__((amdgpu_waves_per_eu(2, 2)))
void decode_seq(
    const float* __restrict__ finp, const float* __restrict__ tpre,
    const int* __restrict__ bnum, const int* __restrict__ padf,
    const float* __restrict__ Wih_t,
    const float* __restrict__ W_fc, const float* __restrict__ b_fc,
    const float* __restrict__ W_tfc, const float* __restrict__ b_tfc,
    const float* __restrict__ Wa, const float* __restrict__ ba,
    const float* __restrict__ ctx, float* __restrict__ out,
    float* __restrict__ xg) {
    __shared__ __align__(16) _Float16 wht16_s[512 * TSTRIDE];  // 139264 B
    __shared__ __align__(16) _Float16 hf16_s[2][128];
    __shared__ __align__(16) _Float16 ht16_s[2][128];
    __shared__ __align__(16) float hf_s[2][128];
    __shared__ float wfcT[128][12];       // also init scratch (counts/offsets)
    __shared__ float wtfc_s[128];
    __shared__ float bfc_s[12];
    __shared__ float cur_res[12];
    __shared__ float v_s[12];
    __shared__ float sc_s[4];             // [0]=ba.ctx [1]=b_tfc [2]=tempo scalar
    __shared__ float tred_s[4];
    __shared__ unsigned long long padw_s[32];
    __shared__ unsigned short run_start_s[300];
    __shared__ short run_cb_s[300];
    __shared__ int nruns_s;

    int t = threadIdx.x, gl = t & 63, gw = t >> 6;
    int b = blockIdx.x;
    bool is_gate = gw < 4;
    int row = (gw << 5) + (gl & 31);      // gate: h-row 0..127
    int kh = gl >> 5;                     // K-half
    if (!is_gate) row = 0;

    // ---- init scratch scan: run-compress beat numbers ----
    int* counts = (int*)&wfcT[0][0];
    int* offs = counts + 512;
    const int* bnb = bnum + (b << 11);
    int bn0 = bnb[0];
    for (int c = t; c < 512; c += 384) {
        int base = c * 4;
        int bvm = (base == 0) ? (bnb[0] - 1) : bnb[base - 1];
        int v0 = bnb[base], v1 = bnb[base + 1], v2 = bnb[base + 2], v3 = bnb[base + 3];
        counts[c] = (v0 != bvm) + (v1 != v0) + (v2 != v1) + (v3 != v2);
    }
    __syncthreads();
    if (gw == 0) {
        int c8[8], s = 0;
#pragma unroll
        for (int j = 0; j < 8; ++j) { c8[j] = counts[gl * 8 + j]; s += c8[j]; }
        int incl = s;
#pragma unroll
        for (int off = 1; off < 64; off <<= 1) {
            int n = __shfl_up(incl, off, 64);
            if (gl >= off) incl += n;
        }
        int run = incl - s;
#pragma unroll
        for (int j = 0; j < 8; ++j) { offs[gl * 8 + j] = run; run += c8[j]; }
        if (gl == 63) nruns_s = incl;
    }
    __syncthreads();
    for (int c = t; c < 512; c += 384) {
        int base = c * 4;
        int bvm = (base == 0) ? (bnb[0] - 1) : bnb[base - 1];
        int v0 = bnb[base], v1 = bnb[base + 1], v2 = bnb[base + 2], v3 = bnb[base + 3];
        int O = offs[c];
        if (v0 != bvm) { run_start_s[O] = (unsigned short)(base + 0); run_cb_s[O] = (short)(v0 - bn0); O++; }
        if (v1 != v0) { run_start_s[O] = (unsigned short)(base + 1); run_cb_s[O] = (short)(v1 - bn0); O++; }
        if (v2 != v1) { run_start_s[O] = (unsigned short)(base + 2); run_cb_s[O] = (short)(v2 - bn0); O++; }
        if (v3 != v2) { run_start_s[O] = (unsigned short)(base + 3); run_cb_s[O] = (short)(v3 - bn0); O++; }
    }
    __syncthreads();  // scratch reads done; wfcT can be filled now
    int nruns_r = nruns_s;

    // ---- weights: 4 gate rows x K-half in 32 named u32x4 (128 VGPR) ----
    u32x4 A0, A1, A2, A3, A4, A5, A6, A7;
    u32x4 Bw0, Bw1, Bw2, Bw3, Bw4, Bw5, Bw6, Bw7;
    u32x4 C0, C1, C2, C3, C4, C5, C6, C7;
    u32x4 Dw0, Dw1, Dw2, Dw3, Dw4, Dw5, Dw6, Dw7;
    {
        int rr = is_gate ? row : 0;
        const u32x4* pa = (const u32x4*)(g_whh_h16 + ((size_t)(rr) << 7) + (kh << 6));
        const u32x4* pb = (const u32x4*)(g_whh_h16 + ((size_t)(rr + 128) << 7) + (kh << 6));
        const u32x4* pc = (const u32x4*)(g_whh_h16 + ((size_t)(rr + 256) << 7) + (kh << 6));
        const u32x4* pd = (const u32x4*)(g_whh_h16 + ((size_t)(rr + 384) << 7) + (kh << 6));
        A0 = pa[0]; A1 = pa[1]; A2 = pa[2]; A3 = pa[3];
        A4 = pa[4]; A5 = pa[5]; A6 = pa[6]; A7 = pa[7];
        Bw0 = pb[0]; Bw1 = pb[1]; Bw2 = pb[2]; Bw3 = pb[3];
        Bw4 = pb[4]; Bw5 = pb[5]; Bw6 = pb[6]; Bw7 = pb[7];
        C0 = pc[0]; C1 = pc[1]; C2 = pc[2]; C3 = pc[3];
        C4 = pc[4]; C5 = pc[5]; C6 = pc[6]; C7 = pc[7];
        Dw0 = pd[0]; Dw1 = pd[1]; Dw2 = pd[2]; Dw3 = pd[3];
        Dw4 = pd[4]; Dw5 = pd[5]; Dw6 = pd[6]; Dw7 = pd[7];
    }
    asm volatile("" : "+v"(A0), "+v"(A1), "+v"(A2), "+v"(A3),
                      "+v"(A4), "+v"(A5), "+v"(A6), "+v"(A7));
    asm volatile("" : "+v"(Bw0), "+v"(Bw1), "+v"(Bw2), "+v"(Bw3),
                      "+v"(Bw4), "+v"(Bw5), "+v"(Bw6), "+v"(Bw7));
    asm volatile("" : "+v"(C0), "+v"(C1), "+v"(C2), "+v"(C3),
                      "+v"(C4), "+v"(C5), "+v"(C6), "+v"(C7));
    asm volatile("" : "+v"(Dw0), "+v"(Dw1), "+v"(Dw2), "+v"(Dw3),
                      "+v"(Dw4), "+v"(Dw5), "+v"(Dw6), "+v"(Dw7));

    // per-row wtail0 (4 gates)
    float wt0a = g_wtail0[row], wt0b = g_wtail0[row + 128],
          wt0c = g_wtail0[row + 256], wt0d = g_wtail0[row + 384];

    // ---- stage Whh_t fp16 into LDS ----
    {
        const uint4* src = (const uint4*)g_wht_h16;
        uint4* dst = (uint4*)wht16_s;
        for (int k = t; k < 512 * TSTRIDE / 8; k += 384) dst[k] = src[k];
    }
    for (int k = t; k < 128 * D_; k += 384) {
        int d = k >> 7, r = k & 127;
        wfcT[r][d] = W_fc[k];
    }
    if (t < 128) {
        wtfc_s[t] = W_tfc[t];
        hf16_s[0][t] = (_Float16)0.f; hf16_s[1][t] = (_Float16)0.f;
        ht16_s[0][t] = (_Float16)0.f; ht16_s[1][t] = (_Float16)0.f;
        hf_s[0][t] = 0.f; hf_s[1][t] = 0.f;
    }
    if (t < D_) {
        bfc_s[t] = b_fc[t];
        cur_res[t] = 0.f;
        float vv = 0.f;
        for (int m = 0; m < D_; ++m) vv += ctx[m] * Wa[m * D_ + t];
        v_s[t] = vv;
    }
    if (t == 10) {
        float cc = 0.f;
        for (int m = 0; m < D_; ++m) cc += ba[m] * ctx[m];
        sc_s[0] = cc;
        sc_s[1] = b_tfc[0];
        sc_s[2] = 0.f;
    }
    if (is_gate) {  // pad bitmask: 4 gate waves x 8 words
        for (int jj = 0; jj < 8; ++jj) {
            int j = gw * 8 + jj;
            int pv = padf[(b << 11) + j * 64 + gl];
            unsigned long long m = __ballot(pv != 0);
            if (gl == 0) padw_s[j] = m;
        }
    }
    __syncthreads();

    const float* finrow = finp + ((size_t)b << 11) * 512;
    float* xgb = xg + ((size_t)(b << 11)) * 16;
    // fin pipeline (kh==0 lanes): rows row,+128,+256,+384 for steps i, i+1
    float fiA_c = 0, fiB_c = 0, fiC_c = 0, fiD_c = 0;
    float fiA_1 = 0, fiB_1 = 0, fiC_1 = 0, fiD_1 = 0;
    float gtA = 0, gtB = 0, gtC = 0, gtD = 0;  // tpre prefetch (run 0: cb=0)
    if (is_gate && kh == 0) {
        fiA_c = finrow[row];       fiB_c = finrow[row + 128];
        fiC_c = finrow[row + 256]; fiD_c = finrow[row + 384];
        fiA_1 = finrow[512 + row];       fiB_1 = finrow[512 + row + 128];
        fiC_1 = finrow[512 + row + 256]; fiD_1 = finrow[512 + row + 384];
        const float* tp0 = tpre + (size_t)(b * NBEATS_) * 512;
        gtA = tp0[row];       gtB = tp0[row + 128];
        gtC = tp0[row + 256]; gtD = tp0[row + 384];
    }
    float cf_r = 0.f, ct_r = 0.f;   // LSTM cell states (register, both halves dup)
    int cur_run = -1, next_start = 0, run_s = 0, S_prev = 0;

    for (int i = 0; i < N_; ++i) {
        bool changed = (i == next_start);
        if (changed) {
            cur_run++;
            S_prev = run_s;
            run_s = i;
            next_start = (cur_run + 1 < nruns_r) ? (int)run_start_s[cur_run + 1] : 4096;
        }
        int wb = i & 1, rb = wb ^ 1;
        int rp = cur_run & 1;            // tempo ping-pong by run parity
        float prev0 = sc_s[2];

        float si = 0.f, sf = 0.f, sg = 0.f, so = 0.f;
        float ti = 0.f, tf = 0.f, tg = 0.f, to_ = 0.f;
        float wA[OUT_], wB[OUT_], wC[OUT_], wD[OUT_];
        float fA2 = 0, fB2 = 0, fC2 = 0, fD2 = 0;

        if (is_gate) {
            if (kh == 0) {  // prefetch fin rows for i+2
                const float* fnx = finrow + (size_t)(i + 2) * 512;
                fA2 = fnx[row];       fB2 = fnx[row + 128];
                fC2 = fnx[row + 256]; fD2 = fnx[row + 384];
            }
            // main matvec: h(i-1) K-half (2-addr broadcast reads)
            {
                const u32x4* hq = (const u32x4*)&hf16_s[rb][0] + (kh << 3);
                u32x4 h0 = hq[0], h1 = hq[1], h2 = hq[2], h3 = hq[3];
                u32x4 h4 = hq[4], h5 = hq[5], h6 = hq[6], h7 = hq[7];
                DQ(A0, h0, si); DQ(A1, h1, si); DQ(A2, h2, si); DQ(A3, h3, si);
                DQ(A4, h4, si); DQ(A5, h5, si); DQ(A6, h6, si); DQ(A7, h7, si);
                DQ(Bw0, h0, sf); DQ(Bw1, h1, sf); DQ(Bw2, h2, sf); DQ(Bw3, h3, sf);
                DQ(Bw4, h4, sf); DQ(Bw5, h5, sf); DQ(Bw6, h6, sf); DQ(Bw7, h7, sf);
                DQ(C0, h0, sg); DQ(C1, h1, sg); DQ(C2, h2, sg); DQ(C3, h3, sg);
                DQ(C4, h4, sg); DQ(C5, h5, sg); DQ(C6, h6, sg); DQ(C7, h7, sg);
                DQ(Dw0, h0, so); DQ(Dw1, h1, so); DQ(Dw2, h2, so); DQ(Dw3, h3, so);
                DQ(Dw4, h4, so); DQ(Dw5, h5, so); DQ(Dw6, h6, so); DQ(Dw7, h7, so);
            }
            if (kh == 0) {
                si += fiA_c; sf += fiB_c; sg += fiC_c; so += fiD_c;
                if (!changed) {
                    si += wt0a * prev0; sf += wt0b * prev0;
                    sg += wt0c * prev0; so += wt0d * prev0;
                }
            }
            // combine K-halves in-wave
            si += __shfl_xor(si, 32, 64);
            sf += __shfl_xor(sf, 32, 64);
            sg += __shfl_xor(sg, 32, 64);
            so += __shfl_xor(so, 32, 64);
            fiA_c = fiA_1; fiB_c = fiB_1; fiC_c = fiC_1; fiD_c = fiD_1;
            fiA_1 = fA2; fiB_1 = fB2; fiC_1 = fC2; fiD_1 = fD2;

            if (changed) {
                if (kh == 0) {  // tempo gate tail coeffs (used after B_c2)
#pragma unroll
                    for (int u = 0; u < OUT_; ++u) {
                        wA[u] = Wih_t[(size_t)row * 203 + 192 + u];
                        wB[u] = Wih_t[(size_t)(row + 128) * 203 + 192 + u];
                        wC[u] = Wih_t[(size_t)(row + 256) * 203 + 192 + u];
                        wD[u] = Wih_t[(size_t)(row + 384) * 203 + 192 + u];
                    }
                }
                // tempo matvec: Whh_t (LDS stream) x ht(prev run)
                const u32x4* tq = (const u32x4*)&ht16_s[rp ^ 1][0] + (kh << 3);
                u32x4 t0 = tq[0], t1 = tq[1], t2 = tq[2], t3 = tq[3];
                u32x4 t4 = tq[4], t5 = tq[5], t6 = tq[6], t7 = tq[7];
                const u32x4* qa = (const u32x4*)(wht16_s + (size_t)row * TSTRIDE + (kh << 6));
                const u32x4* qb = (const u32x4*)(wht16_s + (size_t)(row + 128) * TSTRIDE + (kh << 6));
                const u32x4* qc = (const u32x4*)(wht16_s + (size_t)(row + 256) * TSTRIDE + (kh << 6));
                const u32x4* qd = (const u32x4*)(wht16_s + (size_t)(row + 384) * TSTRIDE + (kh << 6));
#pragma unroll
                for (int k = 0; k < 8; ++k) {
                    u32x4 hh = (k == 0) ? t0 : (k == 1) ? t1 : (k == 2) ? t2 :
                               (k == 3) ? t3 : (k == 4) ? t4 : (k == 5) ? t5 :
                               (k == 6) ? t6 : t7;
                    u32x4 va = qa[k], vb = qb[k], vc = qc[k], vd = qd[k];
                    DQ(va, hh, ti); DQ(vb, hh, tf); DQ(vc, hh, tg); DQ(vd, hh, to_);
                }
            }
        }

        // wave4: finalize step i-1 outputs from hf_s[rb] = h(i-1)
        if (gw == 4 && i > 0) {
            int dd = gl >> 3, rl = gl & 7;
            int d2i = 8 + dd;
            float po1 = 0.f, po2 = 0.f;
            for (int k2 = 0; k2 < 16; ++k2) {
                int r = rl + (k2 << 3);
                float hv = hf_s[rb][r];
                po1 += hv * wfcT[r][dd];
                if (d2i < D_) po2 += hv * wfcT[r][d2i];
            }
            po1 += __shfl_xor(po1, 1); po1 += __shfl_xor(po1, 2); po1 += __shfl_xor(po1, 4);
            po2 += __shfl_xor(po2, 1); po2 += __shfl_xor(po2, 2); po2 += __shfl_xor(po2, 4);
            int pi = i - 1;
            int pd = (int)((padw_s[pi >> 6] >> (pi & 63)) & 1ULL);
            float* orow = out + (size_t)((b << 11) + pi) * OUT_;
            float* xrow = xgb + (size_t)pi * 16;
            if (rl == 0) {
                float od = po1 + bfc_s[dd];
                xrow[dd] = od;
                orow[1 + dd] = pd ? 0.f : od;
                if (d2i < D_) {
                    float od2 = po2 + bfc_s[d2i];
                    xrow[d2i] = od2;
                    orow[1 + d2i] = pd ? 0.f : od2;
                }
            }
            if (gl == 1) orow[0] = pd ? 0.f : prev0;
        }

        if (!changed) {
            if (is_gate) {
                float c2 = sigm_(sf) * cf_r + sigm_(si) * tanh_(sg);
                float h2 = sigm_(so) * tanh_(c2);
                cf_r = c2;
                if (kh == 0) {
                    hf16_s[wb][row] = (_Float16)h2;
                    hf_s[wb][row] = h2;
                }
            }
        } else {
            __syncthreads();  // B_c1: wave4's xg stores drained & visible
            // wave5: attention over [S_prev, i)
            if (gw == 5) {
                int L = i - S_prev;
                const float4* xb = (const float4*)(xgb + (size_t)S_prev * 16);
                float lmax = -1e30f;
                for (int tt = gl; tt < L; tt += 64) {
                    float4 q0 = xb[tt * 4 + 0], q1 = xb[tt * 4 + 1], q2 = xb[tt * 4 + 2];
                    float s = sc_s[0] + q0.x * v_s[0] + q0.y * v_s[1] + q0.z * v_s[2] +
                              q0.w * v_s[3] + q1.x * v_s[4] + q1.y * v_s[5] +
                              q1.z * v_s[6] + q1.w * v_s[7] + q2.x * v_s[8] + q2.y * v_s[9];
                    lmax = fmaxf(lmax, s);
                }
#pragma unroll
                for (int off = 32; off; off >>= 1)
                    lmax = fmaxf(lmax, __shfl_xor(lmax, off, 64));
                float lsum = 0.f, lacc[D_] = {};
                for (int tt = gl; tt < L; tt += 64) {
                    float4 q0 = xb[tt * 4 + 0], q1 = xb[tt * 4 + 1], q2 = xb[tt * 4 + 2];
                    float s = sc_s[0] + q0.x * v_s[0] + q0.y * v_s[1] + q0.z * v_s[2] +
                              q0.w * v_s[3] + q1.x * v_s[4] + q1.y * v_s[5] +
                              q1.z * v_s[6] + q1.w * v_s[7] + q2.x * v_s[8] + q2.y * v_s[9];
                    float w = fexp2_(1.4426950408889634f * (s - lmax));
                    lsum += w;
                    lacc[0] += w * q0.x; lacc[1] += w * q0.y; lacc[2] += w * q0.z;
                    lacc[3] += w * q0.w; lacc[4] += w * q1.x; lacc[5] += w * q1.y;
                    lacc[6] += w * q1.z; lacc[7] += w * q1.w; lacc[8] += w * q2.x;
                    lacc[9] += w * q2.y;
                }
#pragma unroll
                for (int off = 32; off; off >>= 1) {
                    lsum += __shfl_xor(lsum, off, 64);
#pragma unroll
                    for (int d = 0; d < D_; ++d) lacc[d] += __shfl_xor(lacc[d], off, 64);
                }
                if (gl == 0) {
                    if (L > 0) {
                        float inv = 1.0f / lsum;
#pragma unroll
                        for (int d = 0; d < D_; ++d) cur_res[d] = lacc[d] * inv;
                    } else {
#pragma unroll
                        for (int d = 0; d < D_; ++d) cur_res[d] = 0.f;
                    }
                }
            }
            bar_lds_();  // B_c2: cur_res visible
            if (is_gate) {
                if (kh == 0) {
                    float ta = gtA + wA[0] * prev0, tb = gtB + wB[0] * prev0;
                    float tc = gtC + wC[0] * prev0, td = gtD + wD[0] * prev0;
#pragma unroll
                    for (int d = 0; d < D_; ++d) {
                        float cr = cur_res[d];
                        ta += wA[1 + d] * cr; tb += wB[1 + d] * cr;
                        tc += wC[1 + d] * cr; td += wD[1 + d] * cr;
                    }
                    ti += ta; tf += tb; tg += tc; to_ += td;
                }
                ti += __shfl_xor(ti, 32, 64);
                tf += __shfl_xor(tf, 32, 64);
                tg += __shfl_xor(tg, 32, 64);
                to_ += __shfl_xor(to_, 32, 64);
                float tc2 = sigm_(tf) * ct_r + sigm_(ti) * tanh_(tg);
                float th2 = sigm_(to_) * tanh_(tc2);
                ct_r = tc2;
                if (kh == 0) ht16_s[rp][row] = (_Float16)th2;
                float p = (kh == 0) ? th2 * wtfc_s[row] : 0.f;
#pragma unroll
                for (int off = 32; off; off >>= 1) p += __shfl_xor(p, off, 64);
                if (gl == 0) tred_s[gw] = p;
            }
            bar_lds_();  // B_c3: tempo-fc partials ready
            {
                float tnew = tred_s[0] + tred_s[1] + tred_s[2] + tred_s[3] + sc_s[1];
                if (t == 0) sc_s[2] = tnew;
                if (is_gate) {
                    si += wt0a * tnew; sf += wt0b * tnew;
                    sg += wt0c * tnew; so += wt0d * tnew;
                    float c2 = sigm_(sf) * cf_r + sigm_(si) * tanh_(sg);
                    float h2 = sigm_(so) * tanh_(c2);
                    cf_r = c2;
                    if (kh == 0) {
                        hf16_s[wb][row] = (_Float16)h2;
                        hf_s[wb][row] = h2;
                        // prefetch tpre for next run
                        if (cur_run + 1 < nruns_r) {
                            const float* tp = tpre +
                                (size_t)(b * NBEATS_ + (int)run_cb_s[cur_run + 1]) * 512;
                            gtA = tp[row];       gtB = tp[row + 128];
                            gtC = tp[row + 256]; gtD = tp[row + 384];
                        }
                    }
                }
            }
        }
        bar_lds_();  // B_end: h(i) visible for next step
    }

    // epilogue: outputs for i = N_-1 from hf_s[(N_-1)&1]
    if (gw == 4) {
        int pb = (N_ - 1) & 1;
        int dd = gl >> 3, rl = gl & 7;
        int d2i = 8 + dd;
        float po1 = 0.f, po2 = 0.f;
        for (int k2 = 0; k2 < 16; ++k2) {
            int r = rl + (k2 << 3);
            float hv = hf_s[pb][r];
            po1 += hv * wfcT[r][dd];
            if (d2i < D_) po2 += hv * wfcT[r][d2i];
        }
        po1 += __shfl_xor(po1, 1); po1 += __shfl_xor(po1, 2); po1 += __shfl_xor(po1, 4);
        po2 += __shfl_xor(po2, 1); po2 += __shfl_xor(po2, 2); po2 += __shfl_xor(po2, 4);
        int pi = N_ - 1;
        int pd = (int)((padw_s[pi >> 6] >> (pi & 63)) & 1ULL);
        float* orow = out + (size_t)((b << 11) + pi) * OUT_;
        if (rl == 0) {
            orow[1 + dd] = pd ? 0.f : (po1 + bfc_s[dd]);
            if (d2i < D_) orow[1 + d2i] = pd ? 0.f : (po2 + bfc_s[d2i]);
        }
        if (gl == 1) orow[0] = pd ? 0.f : sc_s[2];
    }
}

// ---------------------------------------------------------------------------
extern "C" void kernel_launch(void* const* d_in, const int* in_sizes, int n_in,
                              void* d_out, int out_size, void* d_ws, size_t ws_size,
                              hipStream_t stream) {
    const float* note  = (const float*)d_in[0];
    const float* beat  = (const float*)d_in[1];
    const float* meas  = (const float*)d_in[2];
    const int*   bnum  = (const int*)d_in[3];
    const int*   mnum  = (const int*)d_in[4];
    const float* Wa    = (const float*)d_in[5];
    const float* ba    = (const float*)d_in[6];
    const float* ctx   = (const float*)d_in[7];
    const float* Wih_t = (const float*)d_in[8];
    const float* Whh_t = (const float*)d_in[9];
    const float* bih_t = (const float*)d_in[10];
    const float* bhh_t = (const float*)d_in[11];
    const float* Wih_f = (const float*)d_in[12];
    const float* Whh_f = (const float*)d_in[13];
    const float* bih_f = (const float*)d_in[14];
    const float* bhh_f = (const float*)d_in[15];
    const float* W_fc  = (const float*)d_in[16];
    const float* b_fc  = (const float*)d_in[17];
    const float* W_tfc = (const float*)d_in[18];
    const float* b_tfc = (const float*)d_in[19];
    float* out = (float*)d_out;

    char* ws = (char*)d_ws;
    float* finp = (float*)ws;                                   // 64 MB
    float* tpre = (float*)(ws + (size_t)64 * 1024 * 1024);      // 8 MB
    int*   padf = (int*)(ws + (size_t)72 * 1024 * 1024);        // 128 KB
    float* xg   = (float*)(ws + (size_t)73 * 1024 * 1024);      // 2 MB

    pad_k<<<8192, 256, 0, stream>>>(note, padf);
    fold_whh<<<512, 128, 0, stream>>>(Whh_f, Wih_f, W_fc, b_fc);
    fold_wht<<<512, 128, 0, stream>>>(Whh_t);
    tempo_pre_k<<<dim3(16, 16), 256, 0, stream>>>(beat, meas, bnum, mnum, Wih_t,
                                                  bih_t, bhh_t, tpre);
    fin_pre_gemm<<<dim3(512, 8), 256, 0, stream>>>(note, beat, meas, bnum, mnum,
                                                   Wih_f, bih_f, bhh_f, finp);
    decode_seq<<<16, 384, 0, stream>>>(finp, tpre, bnum, padf, Wih_t,
                                       W_fc, b_fc, W_tfc, b_tfc, Wa, ba, ctx,
                                       out, xg);
}